// Round 2
// baseline (74.989 us; speedup 1.0000x reference)
//
#include <hip/hip_runtime.h>

typedef _Float16 f16x8 __attribute__((ext_vector_type(8)));
typedef float f32x4 __attribute__((ext_vector_type(4)));

#define MROWS 65536
#define BM 64
#define NBLK (MROWS / BM)  // 1024

// ---- d_ws byte offsets ----
#define B1F_OFF 0u       // GEMM1 B frags: [4kt][16nt][64lane][8] f16 = 65536 B
#define B2F_OFF 65536u   // GEMM2 B frags: [8kt][16nt][64lane][8] f16 = 131072 B
#define TP_OFF 196608u   // phone_table @ W1[64:192]: [100][256] f32 = 102400 B
#define TM_OFF 299008u   // midi_table @ W1[192:256]: [128][256] f32 = 131072 B
#define BC_OFF 430080u   // fused bias: [256] f32 = 1024 B
#define WFD_OFF 431104u  // fused f0/dur weights: [64][256] f32 = 65536 B

// Fragment k-slot mapping used consistently for ALL A and B fragments:
//   k = kt*32 + 4*(lane>>4) + (e&3) + 16*(e>>2)
// (A: row = lane&15; B: col = lane&15. C/D: col = lane&15, row = (lane>>4)*4 + reg)

// LDS A-frag swizzle: 16B-granule bijection, XORs addr bits [4:6] with X bits [3:5].
// Makes the pack-phase scattered 8B writes ~conflict-free while keeping the
// contiguous 64-lane b128 frag reads conflict-free.
__device__ __forceinline__ unsigned afoff(unsigned X) {
  return (X * 16u) ^ ((X & 0x38u) << 1);
}

__global__ __launch_bounds__(256) void prep_tables(
    const float* __restrict__ f0_w2, const float* __restrict__ f0_b2,
    const float* __restrict__ ptab, const float* __restrict__ mtab,
    const float* __restrict__ dur_w2, const float* __restrict__ dur_b2,
    const float* __restrict__ W1, const float* __restrict__ pb1,
    float* __restrict__ wsf) {
  const int r = blockIdx.x, n = threadIdx.x;
  if (r < 64) {  // Wfd row r
    float s = 0.f;
    if (r < 32) {
      for (int j = 0; j < 64; ++j) s = fmaf(f0_w2[r * 64 + j], W1[j * 256 + n], s);
    } else {
      for (int j = 0; j < 64; ++j) s = fmaf(dur_w2[(r - 32) * 64 + j], W1[(256 + j) * 256 + n], s);
    }
    wsf[WFD_OFF / 4 + r * 256 + n] = s;
  } else if (r < 164) {  // Tp row
    const int p = r - 64;
    float s = 0.f;
    for (int j = 0; j < 128; ++j) s = fmaf(ptab[p * 128 + j], W1[(64 + j) * 256 + n], s);
    wsf[TP_OFF / 4 + p * 256 + n] = s;
  } else if (r < 292) {  // Tm row
    const int m = r - 164;
    float s = 0.f;
    for (int j = 0; j < 64; ++j) s = fmaf(mtab[m * 64 + j], W1[(192 + j) * 256 + n], s);
    wsf[TM_OFF / 4 + m * 256 + n] = s;
  } else {  // fused bias
    float s = pb1[n];
    for (int j = 0; j < 64; ++j) {
      s = fmaf(f0_b2[j], W1[j * 256 + n], s);
      s = fmaf(dur_b2[j], W1[(256 + j) * 256 + n], s);
    }
    wsf[BC_OFF / 4 + n] = s;
  }
}

__global__ __launch_bounds__(64) void prep_frags(const float* __restrict__ W2, char* __restrict__ ws) {
  const float* Wfd = (const float*)(ws + WFD_OFF);
  const int t = blockIdx.x;
  const int l = threadIdx.x;
  const int qq = l >> 4, c = l & 15;
  if (t < 64) {  // B1: [Wfd; Wfd] duplicated over K=128 (A is hi|lo split)
    const int kt = t >> 4, nt = t & 15;
    f16x8 v;
#pragma unroll
    for (int e = 0; e < 8; ++e) {
      const int k = kt * 32 + 4 * qq + (e & 3) + 16 * (e >> 2);
      v[e] = (_Float16)Wfd[(k & 63) * 256 + nt * 16 + c];
    }
    *(f16x8*)(ws + B1F_OFF + (unsigned)((kt * 16 + nt) * 64 + l) * 16u) = v;
  } else {  // B2 = proj_w2
    const int t2 = t - 64;
    const int kt = t2 >> 4, nt = t2 & 15;
    f16x8 v;
#pragma unroll
    for (int e = 0; e < 8; ++e) {
      const int k = kt * 32 + 4 * qq + (e & 3) + 16 * (e >> 2);
      v[e] = (_Float16)W2[k * 256 + nt * 16 + c];
    }
    *(f16x8*)(ws + B2F_OFF + (unsigned)((kt * 16 + nt) * 64 + l) * 16u) = v;
  }
}

__global__ __launch_bounds__(256, 4) void cond_enc_main(
    const float* __restrict__ f0g, const int* __restrict__ phone,
    const float* __restrict__ durg, const int* __restrict__ midi,
    const float* __restrict__ f0_w1, const float* __restrict__ f0_b1,
    const float* __restrict__ dur_w1, const float* __restrict__ dur_b1,
    const float* __restrict__ ln_g, const float* __restrict__ ln_b,
    const float* __restrict__ pb2, const char* __restrict__ ws,
    float* __restrict__ out) {
  // LDS: [0,32K) A-frags (A1 16K phase 1; A2 32K phase 2, overlaid; swizzled via afoff)
  //      then LN partials [64][9] f32, LN stats [64][2] f32, idx [64][2] int
  __shared__ __align__(16) unsigned char smem[32768 + 2304 + 512 + 512];
  unsigned char* Afrag = smem;
  float* partials = (float*)(smem + 32768);
  float* stats = (float*)(smem + 32768 + 2304);
  int* idxs = (int*)(smem + 32768 + 2304 + 512);

  const int tid = threadIdx.x;
  const int l = tid & 63;
  const int w = tid >> 6;  // wave 0..3 = column group (64 cols each)
  const int q = l >> 4;    // 0..3
  const int c = l & 15;    // 0..15
  const int b = blockIdx.x;
  const int wc = w;

  // prefetch gather indices for the block's 64 rows
  if (tid < BM) {
    idxs[tid * 2 + 0] = phone[b * BM + tid];
    idxs[tid * 2 + 1] = midi[b * BM + tid];
  }

  // ---- Phase 0: a = relu(x*w1+b1), hi/lo f16 split, stored in A-frag order ----
  {
    const int rt = w;             // 4 waves <-> 4 row-tiles of 16
    const int row = rt * 16 + c;  // local row 0..63 (A-frag M on lane&15)
    const int g = b * BM + row;
    const float xf = f0g[g];
    const float xd = durg[g];
#pragma unroll
    for (int kh = 0; kh < 2; ++kh) {  // kh=0: f0 (k' 0..31), kh=1: dur (k' 32..63)
      f16x8 hi, lo;
#pragma unroll
      for (int e = 0; e < 8; ++e) {
        const int ki = 4 * q + (e & 3) + 16 * (e >> 2);  // 0..31
        const float wv = kh ? dur_w1[ki] : f0_w1[ki];
        const float bv = kh ? dur_b1[ki] : f0_b1[ki];
        const float x = kh ? xd : xf;
        const float a = fmaxf(fmaf(x, wv, bv), 0.f);
        const _Float16 h = (_Float16)a;
        hi[e] = h;
        lo[e] = (_Float16)(a - (float)h);
      }
      *(f16x8*)(Afrag + afoff((unsigned)((kh * 4 + rt) * 64 + l))) = hi;        // kt 0,1: hi
      *(f16x8*)(Afrag + afoff((unsigned)(((kh + 2) * 4 + rt) * 64 + l))) = lo;  // kt 2,3: lo
    }
  }
  __syncthreads();

  // ---- Phase 1: GEMM1  h = [a_hi|a_lo] @ [Wfd;Wfd]  (K=128) ----
  const f32x4 zero4 = {0.f, 0.f, 0.f, 0.f};
  f32x4 acc[4][4];
#pragma unroll
  for (int i = 0; i < 4; ++i)
#pragma unroll
    for (int j = 0; j < 4; ++j) acc[i][j] = zero4;
  {
    const f16x8* B1p = (const f16x8*)(ws + B1F_OFF);
#pragma unroll
    for (int kt = 0; kt < 4; ++kt) {
      f16x8 a4[4], b4[4];
#pragma unroll
      for (int i = 0; i < 4; ++i)
        a4[i] = *(const f16x8*)(Afrag + afoff((unsigned)((kt * 4 + i) * 64 + l)));
#pragma unroll
      for (int j = 0; j < 4; ++j) b4[j] = B1p[(kt * 16 + wc * 4 + j) * 64 + l];
#pragma unroll
      for (int i = 0; i < 4; ++i)
#pragma unroll
        for (int j = 0; j < 4; ++j)
          acc[i][j] = __builtin_amdgcn_mfma_f32_16x16x32_f16(a4[i], b4[j], acc[i][j], 0, 0, 0);
    }
  }

  // ---- Phase 1 epilogue: += bias + Tp[phone] + Tm[midi]; LN partial sums ----
  const float* Tp = (const float*)(ws + TP_OFF);
  const float* Tm = (const float*)(ws + TM_OFF);
  const float* bcp = (const float*)(ws + BC_OFF);
  float bcv[4];
#pragma unroll
  for (int j = 0; j < 4; ++j) bcv[j] = bcp[wc * 64 + j * 16 + c];

  float psum[4][4], psq[4][4];
#pragma unroll
  for (int i = 0; i < 4; ++i) {
#pragma unroll
    for (int r = 0; r < 4; ++r) {
      const int row = i * 16 + q * 4 + r;  // C row = (l>>4)*4+reg
      const int ph = idxs[row * 2 + 0];
      const int md = idxs[row * 2 + 1];
      const float* tpr = Tp + ph * 256 + wc * 64 + c;
      const float* tmr = Tm + md * 256 + wc * 64 + c;
      float s = 0.f, ss = 0.f;
#pragma unroll
      for (int j = 0; j < 4; ++j) {
        float v = acc[i][j][r] + bcv[j] + tpr[j * 16] + tmr[j * 16];
        acc[i][j][r] = v;
        s += v;
        ss = fmaf(v, v, ss);
      }
      psum[i][r] = s;
      psq[i][r] = ss;
    }
  }
#pragma unroll
  for (int i = 0; i < 4; ++i)
#pragma unroll
    for (int r = 0; r < 4; ++r) {
      float s = psum[i][r], ss = psq[i][r];
#pragma unroll
      for (int m = 1; m < 16; m <<= 1) {  // reduce across the 16 col-lanes
        s += __shfl_xor(s, m, 64);
        ss += __shfl_xor(ss, m, 64);
      }
      psum[i][r] = s;
      psq[i][r] = ss;
    }
  if (c == 0) {
#pragma unroll
    for (int i = 0; i < 4; ++i)
#pragma unroll
      for (int r = 0; r < 4; ++r) {
        const int row = i * 16 + q * 4 + r;
        partials[row * 9 + wc * 2 + 0] = psum[i][r];
        partials[row * 9 + wc * 2 + 1] = psq[i][r];
      }
  }
  __syncthreads();

  // ---- LN stats (wave 0, one row per lane) ----
  if (w == 0) {
    const int row = l;
    float s = 0.f, ss = 0.f;
#pragma unroll
    for (int x = 0; x < 4; ++x) {
      s += partials[row * 9 + x * 2 + 0];
      ss += partials[row * 9 + x * 2 + 1];
    }
    const float mu = s * (1.f / 256.f);
    const float var = fmaxf(ss * (1.f / 256.f) - mu * mu, 0.f);
    stats[row * 2 + 0] = mu;
    stats[row * 2 + 1] = rsqrtf(var + 1e-5f);
  }
  __syncthreads();

  // ---- Normalize + ReLU + pack into GEMM2 A-fragments (overlay A1 region) ----
  float gv[4], lbv[4];
#pragma unroll
  for (int j = 0; j < 4; ++j) {
    const int col = wc * 64 + j * 16 + c;
    gv[j] = ln_g[col];
    lbv[j] = ln_b[col];
  }
  const int jj = c >> 2;  // col-quad -> target lane's (l'>>4)
  const int tq = c & 3;
#pragma unroll
  for (int i = 0; i < 4; ++i) {
#pragma unroll
    for (int r = 0; r < 4; ++r) {
      const int row = i * 16 + q * 4 + r;
      const float mu = stats[row * 2 + 0];
      const float rstd = stats[row * 2 + 1];
#pragma unroll
      for (int j = 0; j < 4; ++j) {
        float v = fmaf((acc[i][j][r] - mu) * rstd, gv[j], lbv[j]);
        v = fmaxf(v, 0.f);
        const unsigned short u = __builtin_bit_cast(unsigned short, (_Float16)v);
        const unsigned int su = (unsigned int)__shfl_xor((int)u, 1, 64);
        const unsigned int p = (unsigned int)u | (su << 16);
        const unsigned int p2 = (unsigned int)__shfl_xor((int)p, 2, 64);
        if (tq == 0) {  // lane holds 4 consecutive cols packed: write 8B into A2 slot
          const int lp = q * 4 + r + 16 * jj;  // A-frag lane: (row&15) + 16*q'
          const int kt = wc * 2 + (j >> 1);    // k-tile 0..7 (k = col)
          const unsigned X = (unsigned)((kt * 4 + i) * 64 + lp);
          unsigned int* dst = (unsigned int*)(Afrag + afoff(X) + (unsigned)(j & 1) * 8u);
          dst[0] = p;
          dst[1] = p2;
        }
      }
    }
  }
  __syncthreads();

  // ---- Phase 2: GEMM2  out = relu(LN(h)) @ W2 + b2  (K=256) ----
  f32x4 acc2[4][4];
#pragma unroll
  for (int i = 0; i < 4; ++i)
#pragma unroll
    for (int j = 0; j < 4; ++j) acc2[i][j] = zero4;
  {
    const f16x8* B2p = (const f16x8*)(ws + B2F_OFF);
#pragma unroll
    for (int kt = 0; kt < 8; ++kt) {
      f16x8 a4[4], b4[4];
#pragma unroll
      for (int i = 0; i < 4; ++i)
        a4[i] = *(const f16x8*)(Afrag + afoff((unsigned)((kt * 4 + i) * 64 + l)));
#pragma unroll
      for (int j = 0; j < 4; ++j) b4[j] = B2p[(kt * 16 + wc * 4 + j) * 64 + l];
#pragma unroll
      for (int i = 0; i < 4; ++i)
#pragma unroll
        for (int j = 0; j < 4; ++j)
          acc2[i][j] = __builtin_amdgcn_mfma_f32_16x16x32_f16(a4[i], b4[j], acc2[i][j], 0, 0, 0);
    }
  }
  float b2v[4];
#pragma unroll
  for (int j = 0; j < 4; ++j) b2v[j] = pb2[wc * 64 + j * 16 + c];
#pragma unroll
  for (int i = 0; i < 4; ++i)
#pragma unroll
    for (int j = 0; j < 4; ++j)
#pragma unroll
      for (int r = 0; r < 4; ++r) {
        const int grow = b * BM + i * 16 + q * 4 + r;
        const int col = wc * 64 + j * 16 + c;
        out[grow * 256 + col] = acc2[i][j][r] + b2v[j];
      }
}

extern "C" void kernel_launch(void* const* d_in, const int* in_sizes, int n_in,
                              void* d_out, int out_size, void* d_ws, size_t ws_size,
                              hipStream_t stream) {
  (void)in_sizes; (void)n_in; (void)out_size; (void)ws_size;
  const float* f0 = (const float*)d_in[0];
  const int* phone = (const int*)d_in[1];
  const float* dur = (const float*)d_in[2];
  const int* midi = (const int*)d_in[3];
  const float* f0_w1 = (const float*)d_in[4];
  const float* f0_b1 = (const float*)d_in[5];
  const float* f0_w2 = (const float*)d_in[6];
  const float* f0_b2 = (const float*)d_in[7];
  const float* ptab = (const float*)d_in[8];
  const float* mtab = (const float*)d_in[9];
  const float* dur_w1 = (const float*)d_in[10];
  const float* dur_b1 = (const float*)d_in[11];
  const float* dur_w2 = (const float*)d_in[12];
  const float* dur_b2 = (const float*)d_in[13];
  const float* W1 = (const float*)d_in[14];
  const float* pb1 = (const float*)d_in[15];
  const float* ln_g = (const float*)d_in[16];
  const float* ln_b = (const float*)d_in[17];
  const float* W2 = (const float*)d_in[18];
  const float* pb2 = (const float*)d_in[19];
  char* ws = (char*)d_ws;
  float* out = (float*)d_out;

  prep_tables<<<293, 256, 0, stream>>>(f0_w2, f0_b2, ptab, mtab, dur_w2, dur_b2, W1, pb1, (float*)ws);
  prep_frags<<<192, 64, 0, stream>>>(W2, ws);
  cond_enc_main<<<NBLK, 256, 0, stream>>>(f0, phone, dur, midi, f0_w1, f0_b1, dur_w1, dur_b1,
                                          ln_g, ln_b, pb2, ws, out);
}

// Round 3
// 52.823 us; speedup vs baseline: 1.4196x; 1.4196x over previous
//
#include <hip/hip_runtime.h>

typedef _Float16 f16x8 __attribute__((ext_vector_type(8)));
typedef float f32x4 __attribute__((ext_vector_type(4)));

#define MROWS 65536
#define BM 64
#define NBLK (MROWS / BM)  // 1024

// ---- d_ws byte offsets ----
#define B1F_OFF 0u       // GEMM1 B frags: [4kt][16nt][64lane][8] f16 = 65536 B
#define B2F_OFF 65536u   // GEMM2 B frags: [8kt][16nt][64lane][8] f16 = 131072 B
#define TP_OFF 196608u   // phone_table @ W1[64:192]: [100][256] f32 = 102400 B
#define TM_OFF 299008u   // midi_table @ W1[192:256]: [128][256] f32 = 131072 B
#define BC_OFF 430080u   // fused bias: [256] f32 = 1024 B
#define WFD_OFF 431104u  // fused f0/dur weights: [64][256] f32 = 65536 B

// Fragment k-slot mapping used consistently for ALL A and B fragments:
//   k = kt*32 + 4*(lane>>4) + (e&3) + 16*(e>>2)
// (A: row = lane&15; B: col = lane&15. C/D: col = lane&15, row = (lane>>4)*4 + reg)

// LDS A-frag swizzle: 16B-granule bijection, XORs addr bits [4:6] with X bits [3:5].
// Pack-phase scattered 8B writes become ~conflict-free (measured: 3.15M -> 0)
// while contiguous 64-lane b128 frag reads stay conflict-free.
__device__ __forceinline__ unsigned afoff(unsigned X) {
  return (X * 16u) ^ ((X & 0x38u) << 1);
}

__global__ __launch_bounds__(256) void prep_tables(
    const float* __restrict__ f0_w2, const float* __restrict__ f0_b2,
    const float* __restrict__ ptab, const float* __restrict__ mtab,
    const float* __restrict__ dur_w2, const float* __restrict__ dur_b2,
    const float* __restrict__ W1, const float* __restrict__ pb1,
    float* __restrict__ wsf) {
  const int r = blockIdx.x, n = threadIdx.x;
  if (r < 64) {  // Wfd row r
    float s = 0.f;
    if (r < 32) {
      for (int j = 0; j < 64; ++j) s = fmaf(f0_w2[r * 64 + j], W1[j * 256 + n], s);
    } else {
      for (int j = 0; j < 64; ++j) s = fmaf(dur_w2[(r - 32) * 64 + j], W1[(256 + j) * 256 + n], s);
    }
    wsf[WFD_OFF / 4 + r * 256 + n] = s;
  } else if (r < 164) {  // Tp row
    const int p = r - 64;
    float s = 0.f;
    for (int j = 0; j < 128; ++j) s = fmaf(ptab[p * 128 + j], W1[(64 + j) * 256 + n], s);
    wsf[TP_OFF / 4 + p * 256 + n] = s;
  } else if (r < 292) {  // Tm row
    const int m = r - 164;
    float s = 0.f;
    for (int j = 0; j < 64; ++j) s = fmaf(mtab[m * 64 + j], W1[(192 + j) * 256 + n], s);
    wsf[TM_OFF / 4 + m * 256 + n] = s;
  } else {  // fused bias
    float s = pb1[n];
    for (int j = 0; j < 64; ++j) {
      s = fmaf(f0_b2[j], W1[j * 256 + n], s);
      s = fmaf(dur_b2[j], W1[(256 + j) * 256 + n], s);
    }
    wsf[BC_OFF / 4 + n] = s;
  }
}

__global__ __launch_bounds__(64) void prep_frags(const float* __restrict__ W2, char* __restrict__ ws) {
  const float* Wfd = (const float*)(ws + WFD_OFF);
  const int t = blockIdx.x;
  const int l = threadIdx.x;
  const int qq = l >> 4, c = l & 15;
  if (t < 64) {  // B1: [Wfd; Wfd] duplicated over K=128 (A is hi|lo split)
    const int kt = t >> 4, nt = t & 15;
    f16x8 v;
#pragma unroll
    for (int e = 0; e < 8; ++e) {
      const int k = kt * 32 + 4 * qq + (e & 3) + 16 * (e >> 2);
      v[e] = (_Float16)Wfd[(k & 63) * 256 + nt * 16 + c];
    }
    *(f16x8*)(ws + B1F_OFF + (unsigned)((kt * 16 + nt) * 64 + l) * 16u) = v;
  } else {  // B2 = proj_w2
    const int t2 = t - 64;
    const int kt = t2 >> 4, nt = t2 & 15;
    f16x8 v;
#pragma unroll
    for (int e = 0; e < 8; ++e) {
      const int k = kt * 32 + 4 * qq + (e & 3) + 16 * (e >> 2);
      v[e] = (_Float16)W2[k * 256 + nt * 16 + c];
    }
    *(f16x8*)(ws + B2F_OFF + (unsigned)((kt * 16 + nt) * 64 + l) * 16u) = v;
  }
}

__global__ __launch_bounds__(256, 2) void cond_enc_main(
    const float* __restrict__ f0g, const int* __restrict__ phone,
    const float* __restrict__ durg, const int* __restrict__ midi,
    const float* __restrict__ f0_w1, const float* __restrict__ f0_b1,
    const float* __restrict__ dur_w1, const float* __restrict__ dur_b1,
    const float* __restrict__ ln_g, const float* __restrict__ ln_b,
    const float* __restrict__ pb2, const char* __restrict__ ws,
    float* __restrict__ out) {
  // LDS: [0,32K) A-frags (A1 16K phase 1; A2 32K phase 2, overlaid; swizzled via afoff)
  //      then LN partials [64][9] f32, LN stats [64][2] f32, idx [64][2] int
  __shared__ __align__(16) unsigned char smem[32768 + 2304 + 512 + 512];
  unsigned char* Afrag = smem;
  float* partials = (float*)(smem + 32768);
  float* stats = (float*)(smem + 32768 + 2304);
  int* idxs = (int*)(smem + 32768 + 2304 + 512);

  const int tid = threadIdx.x;
  const int l = tid & 63;
  const int w = tid >> 6;  // wave 0..3 = column group (64 cols each)
  const int q = l >> 4;    // 0..3
  const int c = l & 15;    // 0..15
  const int b = blockIdx.x;
  const int wc = w;

  // prefetch gather indices for the block's 64 rows
  if (tid < BM) {
    idxs[tid * 2 + 0] = phone[b * BM + tid];
    idxs[tid * 2 + 1] = midi[b * BM + tid];
  }

  // ---- Phase 0: a = relu(x*w1+b1), hi/lo f16 split, stored in A-frag order ----
  {
    const int rt = w;             // 4 waves <-> 4 row-tiles of 16
    const int row = rt * 16 + c;  // local row 0..63 (A-frag M on lane&15)
    const int g = b * BM + row;
    const float xf = f0g[g];
    const float xd = durg[g];
#pragma unroll
    for (int kh = 0; kh < 2; ++kh) {  // kh=0: f0 (k' 0..31), kh=1: dur (k' 32..63)
      f16x8 hi, lo;
#pragma unroll
      for (int e = 0; e < 8; ++e) {
        const int ki = 4 * q + (e & 3) + 16 * (e >> 2);  // 0..31
        const float wv = kh ? dur_w1[ki] : f0_w1[ki];
        const float bv = kh ? dur_b1[ki] : f0_b1[ki];
        const float x = kh ? xd : xf;
        const float a = fmaxf(fmaf(x, wv, bv), 0.f);
        const _Float16 h = (_Float16)a;
        hi[e] = h;
        lo[e] = (_Float16)(a - (float)h);
      }
      *(f16x8*)(Afrag + afoff((unsigned)((kh * 4 + rt) * 64 + l))) = hi;        // kt 0,1: hi
      *(f16x8*)(Afrag + afoff((unsigned)(((kh + 2) * 4 + rt) * 64 + l))) = lo;  // kt 2,3: lo
    }
  }
  __syncthreads();

  // ---- Phase 1: GEMM1  h = [a_hi|a_lo] @ [Wfd;Wfd]  (K=128) ----
  // acc is REUSED for GEMM2 (re-zeroed after the pack phase) to keep peak
  // VGPR pressure < 128 (round-2 lesson: a 64-VGPR cap spilled 130+ MB to scratch).
  const f32x4 zero4 = {0.f, 0.f, 0.f, 0.f};
  f32x4 acc[4][4];
#pragma unroll
  for (int i = 0; i < 4; ++i)
#pragma unroll
    for (int j = 0; j < 4; ++j) acc[i][j] = zero4;
  {
    const f16x8* B1p = (const f16x8*)(ws + B1F_OFF);
#pragma unroll
    for (int kt = 0; kt < 4; ++kt) {
      f16x8 a4[4], b4[4];
#pragma unroll
      for (int i = 0; i < 4; ++i)
        a4[i] = *(const f16x8*)(Afrag + afoff((unsigned)((kt * 4 + i) * 64 + l)));
#pragma unroll
      for (int j = 0; j < 4; ++j) b4[j] = B1p[(kt * 16 + wc * 4 + j) * 64 + l];
#pragma unroll
      for (int i = 0; i < 4; ++i)
#pragma unroll
        for (int j = 0; j < 4; ++j)
          acc[i][j] = __builtin_amdgcn_mfma_f32_16x16x32_f16(a4[i], b4[j], acc[i][j], 0, 0, 0);
    }
  }

  // ---- Phase 1 epilogue: += bias + Tp[phone] + Tm[midi]; LN partial sums ----
  const float* Tp = (const float*)(ws + TP_OFF);
  const float* Tm = (const float*)(ws + TM_OFF);
  const float* bcp = (const float*)(ws + BC_OFF);
  float bcv[4];
#pragma unroll
  for (int j = 0; j < 4; ++j) bcv[j] = bcp[wc * 64 + j * 16 + c];

  float psum[4][4], psq[4][4];
#pragma unroll
  for (int i = 0; i < 4; ++i) {
#pragma unroll
    for (int r = 0; r < 4; ++r) {
      const int row = i * 16 + q * 4 + r;  // C row = (l>>4)*4+reg
      const int ph = idxs[row * 2 + 0];
      const int md = idxs[row * 2 + 1];
      const float* tpr = Tp + ph * 256 + wc * 64 + c;
      const float* tmr = Tm + md * 256 + wc * 64 + c;
      float s = 0.f, ss = 0.f;
#pragma unroll
      for (int j = 0; j < 4; ++j) {
        float v = acc[i][j][r] + bcv[j] + tpr[j * 16] + tmr[j * 16];
        acc[i][j][r] = v;
        s += v;
        ss = fmaf(v, v, ss);
      }
      psum[i][r] = s;
      psq[i][r] = ss;
    }
  }
#pragma unroll
  for (int i = 0; i < 4; ++i)
#pragma unroll
    for (int r = 0; r < 4; ++r) {
      float s = psum[i][r], ss = psq[i][r];
#pragma unroll
      for (int m = 1; m < 16; m <<= 1) {  // reduce across the 16 col-lanes
        s += __shfl_xor(s, m, 64);
        ss += __shfl_xor(ss, m, 64);
      }
      psum[i][r] = s;
      psq[i][r] = ss;
    }
  if (c == 0) {
#pragma unroll
    for (int i = 0; i < 4; ++i)
#pragma unroll
      for (int r = 0; r < 4; ++r) {
        const int row = i * 16 + q * 4 + r;
        partials[row * 9 + wc * 2 + 0] = psum[i][r];
        partials[row * 9 + wc * 2 + 1] = psq[i][r];
      }
  }
  __syncthreads();

  // ---- LN stats (wave 0, one row per lane) ----
  if (w == 0) {
    const int row = l;
    float s = 0.f, ss = 0.f;
#pragma unroll
    for (int x = 0; x < 4; ++x) {
      s += partials[row * 9 + x * 2 + 0];
      ss += partials[row * 9 + x * 2 + 1];
    }
    const float mu = s * (1.f / 256.f);
    const float var = fmaxf(ss * (1.f / 256.f) - mu * mu, 0.f);
    stats[row * 2 + 0] = mu;
    stats[row * 2 + 1] = rsqrtf(var + 1e-5f);
  }
  __syncthreads();

  // ---- Normalize + ReLU + pack into GEMM2 A-fragments (overlay A1 region) ----
  float gv[4], lbv[4];
#pragma unroll
  for (int j = 0; j < 4; ++j) {
    const int col = wc * 64 + j * 16 + c;
    gv[j] = ln_g[col];
    lbv[j] = ln_b[col];
  }
  const int jj = c >> 2;  // col-quad -> target lane's (l'>>4)
  const int tq = c & 3;
#pragma unroll
  for (int i = 0; i < 4; ++i) {
#pragma unroll
    for (int r = 0; r < 4; ++r) {
      const int row = i * 16 + q * 4 + r;
      const float mu = stats[row * 2 + 0];
      const float rstd = stats[row * 2 + 1];
#pragma unroll
      for (int j = 0; j < 4; ++j) {
        float v = fmaf((acc[i][j][r] - mu) * rstd, gv[j], lbv[j]);
        v = fmaxf(v, 0.f);
        const unsigned short u = __builtin_bit_cast(unsigned short, (_Float16)v);
        const unsigned int su = (unsigned int)__shfl_xor((int)u, 1, 64);
        const unsigned int p = (unsigned int)u | (su << 16);
        const unsigned int p2 = (unsigned int)__shfl_xor((int)p, 2, 64);
        if (tq == 0) {  // lane holds 4 consecutive cols packed: write 8B into A2 slot
          const int lp = q * 4 + r + 16 * jj;  // A-frag lane: (row&15) + 16*q'
          const int kt = wc * 2 + (j >> 1);    // k-tile 0..7 (k = col)
          const unsigned X = (unsigned)((kt * 4 + i) * 64 + lp);
          unsigned int* dst = (unsigned int*)(Afrag + afoff(X) + (unsigned)(j & 1) * 8u);
          dst[0] = p;
          dst[1] = p2;
        }
      }
    }
  }
  __syncthreads();

  // ---- Phase 2: GEMM2  out = relu(LN(h)) @ W2 + b2  (K=256) ----
#pragma unroll
  for (int i = 0; i < 4; ++i)
#pragma unroll
    for (int j = 0; j < 4; ++j) acc[i][j] = zero4;
  {
    const f16x8* B2p = (const f16x8*)(ws + B2F_OFF);
#pragma unroll
    for (int kt = 0; kt < 8; ++kt) {
      f16x8 a4[4], b4[4];
#pragma unroll
      for (int i = 0; i < 4; ++i)
        a4[i] = *(const f16x8*)(Afrag + afoff((unsigned)((kt * 4 + i) * 64 + l)));
#pragma unroll
      for (int j = 0; j < 4; ++j) b4[j] = B2p[(kt * 16 + wc * 4 + j) * 64 + l];
#pragma unroll
      for (int i = 0; i < 4; ++i)
#pragma unroll
        for (int j = 0; j < 4; ++j)
          acc[i][j] = __builtin_amdgcn_mfma_f32_16x16x32_f16(a4[i], b4[j], acc[i][j], 0, 0, 0);
    }
  }
  float b2v[4];
#pragma unroll
  for (int j = 0; j < 4; ++j) b2v[j] = pb2[wc * 64 + j * 16 + c];
#pragma unroll
  for (int i = 0; i < 4; ++i)
#pragma unroll
    for (int j = 0; j < 4; ++j)
#pragma unroll
      for (int r = 0; r < 4; ++r) {
        const int grow = b * BM + i * 16 + q * 4 + r;
        const int col = wc * 64 + j * 16 + c;
        out[grow * 256 + col] = acc[i][j][r] + b2v[j];
      }
}

extern "C" void kernel_launch(void* const* d_in, const int* in_sizes, int n_in,
                              void* d_out, int out_size, void* d_ws, size_t ws_size,
                              hipStream_t stream) {
  (void)in_sizes; (void)n_in; (void)out_size; (void)ws_size;
  const float* f0 = (const float*)d_in[0];
  const int* phone = (const int*)d_in[1];
  const float* dur = (const float*)d_in[2];
  const int* midi = (const int*)d_in[3];
  const float* f0_w1 = (const float*)d_in[4];
  const float* f0_b1 = (const float*)d_in[5];
  const float* f0_w2 = (const float*)d_in[6];
  const float* f0_b2 = (const float*)d_in[7];
  const float* ptab = (const float*)d_in[8];
  const float* mtab = (const float*)d_in[9];
  const float* dur_w1 = (const float*)d_in[10];
  const float* dur_b1 = (const float*)d_in[11];
  const float* dur_w2 = (const float*)d_in[12];
  const float* dur_b2 = (const float*)d_in[13];
  const float* W1 = (const float*)d_in[14];
  const float* pb1 = (const float*)d_in[15];
  const float* ln_g = (const float*)d_in[16];
  const float* ln_b = (const float*)d_in[17];
  const float* W2 = (const float*)d_in[18];
  const float* pb2 = (const float*)d_in[19];
  char* ws = (char*)d_ws;
  float* out = (float*)d_out;

  prep_tables<<<293, 256, 0, stream>>>(f0_w2, f0_b2, ptab, mtab, dur_w2, dur_b2, W1, pb1, (float*)ws);
  prep_frags<<<192, 64, 0, stream>>>(W2, ws);
  cond_enc_main<<<NBLK, 256, 0, stream>>>(f0, phone, dur, midi, f0_w1, f0_b1, dur_w1, dur_b1,
                                          ln_g, ln_b, pb2, ws, out);
}